// Round 19
// baseline (54.739 us; speedup 1.0000x reference)
//
#include <hip/hip_runtime.h>
#include <hip/hip_bf16.h>

#define SEQL 4096
#define MROWS 32768
#define DMODEL 512
#define KFULL 1024
#define PSTR 516   // padded P_lds row stride (floats); 516*4B is 16B-aligned, lane-bank stride 4

typedef __attribute__((ext_vector_type(8))) short bf16x8;
typedef __attribute__((ext_vector_type(4))) unsigned u32x4;
typedef __attribute__((ext_vector_type(4))) float f32x4;

__device__ __forceinline__ unsigned cvt_pk2(float a, float b) {
    unsigned r;
    asm("v_cvt_pk_bf16_f32 %0, %1, %2" : "=v"(r) : "v"(a), "v"(b));
    return r;
}

__device__ __forceinline__ float nonsat(float x) {
    float y = x;
    #pragma unroll
    for (int i = 0; i < 5; ++i) {
        float y2  = y * y;
        float num = __builtin_fmaf(y2 * y, 0.66666667f, x);
        y = num * __builtin_amdgcn_rcpf(y2 + 1.0f);
    }
    return y;
}

// W (512x1024 f32 [n][k]) -> fragment-tiled bf16:
// frag f = (k/32)*32 + (n/16); lane = ((k/8)&3)*16 + (n&15); elems k..k+7.
__global__ __launch_bounds__(256) void cvt_w(const float* __restrict__ W,
                                             short* __restrict__ Wbf) {
    int t8 = blockIdx.x * 256 + threadIdx.x;
    int n = t8 >> 7;
    int k = (t8 & 127) << 3;
    f32x4 lo = *(const f32x4*)(W + (size_t)n * KFULL + k);
    f32x4 hi = *(const f32x4*)(W + (size_t)n * KFULL + k + 4);
    u32x4 v;
    v[0] = cvt_pk2(lo[0], lo[1]); v[1] = cvt_pk2(lo[2], lo[3]);
    v[2] = cvt_pk2(hi[0], hi[1]); v[3] = cvt_pk2(hi[2], hi[3]);
    int f    = (k >> 5) * 32 + (n >> 4);
    int lane = ((k >> 3) & 3) * 16 + (n & 15);
    *(u32x4*)(Wbf + (size_t)f * 512 + lane * 8) = v;
}

// main (fully fused): out = nonsat(LN(x @ W1^T + (pe @ W2^T + bias)[m>>3]))
// 128 rows x 512 cols per block, 8 waves (2m x 4n), BK=32, grid 256 (1/CU).
// Phase 0: in-kernel pe-GEMM (block-exclusive 16 P-rows), 2-deep software-
//   pipelined (prefetch kf+1 W2-frags + pe-chunk during kf's MFMAs); main
//   k-step-0 loads issued BEFORE phase 0 so they land during its compute.
// Phase 1: r15's verified K-loop — double-buffered LDS W (frag layout,
//   flat copy) + x (frag layout, write-side permutation), 1 barrier/k-step.
__global__ __launch_bounds__(512, 2) void main_fused(
    const float* __restrict__ x, const short* __restrict__ Wbf,
    const float* __restrict__ pe, const float* __restrict__ bias,
    const float* __restrict__ gamma, const float* __restrict__ beta,
    float* __restrict__ out)
{
    __shared__ __align__(16) short Wl[2][16384];   // 64 KB
    __shared__ __align__(16) short As[2][4096];    // 16 KB
    __shared__ float P_lds[16 * PSTR];             // 33 KB (padded stride)
    __shared__ float GB[2][512];                   // 4 KB
    __shared__ float red[4][128][2];               // 4 KB

    const int tid  = threadIdx.x;
    const int wid  = tid >> 6;
    const int wm   = wid >> 2;
    const int wn   = wid & 3;
    const int lane = tid & 63;
    const int l4   = lane & 15;
    const int kg   = lane >> 4;
    const int m0   = blockIdx.x * 128;
    const int l0   = m0 >> 3;           // 16 exclusive P rows per block

    // x: thread -> row tid/4, k-chunk (tid&3)*8 (8 fp32 = 32B, coalesced)
    const float* xp = x + (size_t)(m0 + (tid >> 2)) * DMODEL + (tid & 3) * 8;
    const int as_adr = wid * 512 + ((tid & 3) * 16 + ((tid >> 2) & 15)) * 8;

    u32x4 wr[4];
    f32x4 xr0, xr1;

    #define LOADS(kf)  do {                                                     \
        const short* wg = Wbf + (size_t)(kf) * 16384 + tid * 8;                 \
        wr[0] = *(const u32x4*)(wg);                                            \
        wr[1] = *(const u32x4*)(wg + 4096);                                     \
        wr[2] = *(const u32x4*)(wg + 8192);                                     \
        wr[3] = *(const u32x4*)(wg + 12288);                                    \
        xr0 = *(const f32x4*)(xp + (kf) * 32);                                  \
        xr1 = *(const f32x4*)(xp + (kf) * 32 + 4);                              \
    } while (0)

    #define WRITES(b)  do {                                                     \
        *(u32x4*)&Wl[b][tid * 8]         = wr[0];                               \
        *(u32x4*)&Wl[b][tid * 8 + 4096]  = wr[1];                               \
        *(u32x4*)&Wl[b][tid * 8 + 8192]  = wr[2];                               \
        *(u32x4*)&Wl[b][tid * 8 + 12288] = wr[3];                               \
        u32x4 v;                                                                \
        v[0] = cvt_pk2(xr0[0], xr0[1]); v[1] = cvt_pk2(xr0[2], xr0[3]);         \
        v[2] = cvt_pk2(xr1[0], xr1[1]); v[3] = cvt_pk2(xr1[2], xr1[3]);         \
        *(u32x4*)&As[b][as_adr] = v;                                            \
    } while (0)

    // ================= Phase 0: pipelined pe-GEMM -> P_lds ================
    {
        const float* peb = pe + (size_t)(l0 + l4) * DMODEL + kg * 8;

        #define PH0_LOAD(kf, AW, PL, PH) do {                                    \
            _Pragma("unroll")                                                    \
            for (int t_ = 0; t_ < 4; ++t_)                                       \
                AW[t_] = *(const bf16x8*)(Wbf +                                  \
                    (size_t)((16 + (kf)) * 32 + wid * 4 + t_) * 512 + lane * 8); \
            PL = *(const f32x4*)(peb + (kf) * 32);                               \
            PH = *(const f32x4*)(peb + (kf) * 32 + 4);                           \
        } while (0)

        bf16x8 awA[4], awB[4];
        f32x4 plA, phA, plB, phB;
        f32x4 accp[4];
        #pragma unroll
        for (int t = 0; t < 4; ++t) accp[t] = (f32x4){0.f, 0.f, 0.f, 0.f};

        PH0_LOAD(0, awA, plA, phA);
        LOADS(0);   // phase-1 step-0 loads land during phase-0 compute

        #pragma unroll
        for (int kf = 0; kf < 16; ++kf) {
            if ((kf & 1) == 0) {
                if (kf < 15) PH0_LOAD(kf + 1, awB, plB, phB);
                union { u32x4 u; bf16x8 s; } cv;
                cv.u[0] = cvt_pk2(plA[0], plA[1]); cv.u[1] = cvt_pk2(plA[2], plA[3]);
                cv.u[2] = cvt_pk2(phA[0], phA[1]); cv.u[3] = cvt_pk2(phA[2], phA[3]);
                #pragma unroll
                for (int t = 0; t < 4; ++t)
                    accp[t] = __builtin_amdgcn_mfma_f32_16x16x32_bf16(awA[t], cv.s, accp[t], 0, 0, 0);
            } else {
                if (kf < 15) PH0_LOAD(kf + 1, awA, plA, phA);
                union { u32x4 u; bf16x8 s; } cv;
                cv.u[0] = cvt_pk2(plB[0], plB[1]); cv.u[1] = cvt_pk2(plB[2], plB[3]);
                cv.u[2] = cvt_pk2(phB[0], phB[1]); cv.u[3] = cvt_pk2(phB[2], phB[3]);
                #pragma unroll
                for (int t = 0; t < 4; ++t)
                    accp[t] = __builtin_amdgcn_mfma_f32_16x16x32_bf16(awB[t], cv.s, accp[t], 0, 0, 0);
            }
        }
        #undef PH0_LOAD

        // C layout: col(l4) = pe row l, row(kg*4+j) = n within frag
        #pragma unroll
        for (int t = 0; t < 4; ++t) {
            int n = wid * 64 + t * 16 + kg * 4;
            f32x4 b4 = *(const f32x4*)(bias + n);
            *(f32x4*)&P_lds[l4 * PSTR + n] = accp[t] + b4;
        }
    }

    // ================= Phase 1: main GEMM (r15 skeleton) ===================
    f32x4 acc[4][8];
    #pragma unroll
    for (int mi = 0; mi < 4; ++mi)
        #pragma unroll
        for (int t = 0; t < 8; ++t) acc[mi][t] = (f32x4){0.f,0.f,0.f,0.f};

    WRITES(0);
    LOADS(1);

    f32x4 gb;

    #pragma unroll
    for (int kf = 0; kf < 16; ++kf) {
        const int cur = kf & 1;
        __syncthreads();
        if (kf < 15) WRITES(cur ^ 1);
        if (kf < 14) LOADS(kf + 2);
        if (kf == 13) {
            if (tid < 256) {
                const float* gsrc = (tid < 128) ? (gamma + tid * 4) : (beta + (tid - 128) * 4);
                gb = *(const f32x4*)gsrc;
            }
        }
        bf16x8 aw[8];
        #pragma unroll
        for (int t = 0; t < 8; ++t)
            aw[t] = *(const bf16x8*)&Wl[cur][(wn * 8 + t) * 512 + lane * 8];
        bf16x8 bx[4];
        #pragma unroll
        for (int mi = 0; mi < 4; ++mi)
            bx[mi] = *(const bf16x8*)&As[cur][(wm * 4 + mi) * 512 + lane * 8];
        __builtin_amdgcn_s_setprio(1);
        #pragma unroll
        for (int t = 0; t < 8; ++t)
            #pragma unroll
            for (int mi = 0; mi < 4; ++mi)
                acc[mi][t] = __builtin_amdgcn_mfma_f32_16x16x32_bf16(aw[t], bx[mi], acc[mi][t], 0, 0, 0);
        __builtin_amdgcn_s_setprio(0);
    }
    #undef LOADS
    #undef WRITES

    // ---- stage gamma/beta to LDS (P already resident in P_lds) ----
    if (tid < 256) {
        if (tid < 128) *(f32x4*)&GB[0][tid * 4]         = gb;
        else           *(f32x4*)&GB[1][(tid - 128) * 4] = gb;
    }
    __syncthreads();

    // ---- add P (broadcast LDS reads) ----
    #pragma unroll
    for (int mi = 0; mi < 4; ++mi) {
        int lp = wm * 8 + mi * 2 + (l4 >> 3);
        #pragma unroll
        for (int t = 0; t < 8; ++t) {
            f32x4 p4 = *(const f32x4*)&P_lds[lp * PSTR + wn * 128 + t * 16 + kg * 4];
            acc[mi][t] += p4;
        }
    }

    // ---- LN stats ----
    float S[4], Q[4];
    #pragma unroll
    for (int mi = 0; mi < 4; ++mi) {
        float s = 0.f, q = 0.f;
        #pragma unroll
        for (int t = 0; t < 8; ++t)
            #pragma unroll
            for (int j = 0; j < 4; ++j) {
                float v = acc[mi][t][j];
                s += v; q = __builtin_fmaf(v, v, q);
            }
        s += __shfl_xor(s, 16); q += __shfl_xor(q, 16);
        s += __shfl_xor(s, 32); q += __shfl_xor(q, 32);
        S[mi] = s; Q[mi] = q;
    }
    if (lane < 16) {
        #pragma unroll
        for (int mi = 0; mi < 4; ++mi) {
            red[wn][wm * 64 + mi * 16 + l4][0] = S[mi];
            red[wn][wm * 64 + mi * 16 + l4][1] = Q[mi];
        }
    }
    __syncthreads();

    // ---- normalize + nonsat + stores ----
    #pragma unroll
    for (int mi = 0; mi < 4; ++mi) {
        int r = wm * 64 + mi * 16 + l4;
        float Ss = red[0][r][0] + red[1][r][0] + red[2][r][0] + red[3][r][0];
        float Qs = red[0][r][1] + red[1][r][1] + red[2][r][1] + red[3][r][1];
        float mean = Ss * (1.0f / 512.0f);
        float var  = Qs * (1.0f / 512.0f) - mean * mean;
        float rstd = rsqrtf(var + 1e-5f);
        float nmrs = -mean * rstd;
        float* orow = out + (size_t)(m0 + r) * DMODEL;
        #pragma unroll
        for (int t = 0; t < 8; ++t) {
            int n = wn * 128 + t * 16 + kg * 4;
            f32x4 g4 = *(const f32x4*)&GB[0][n];
            f32x4 b4 = *(const f32x4*)&GB[1][n];
            f32x4 o;
            #pragma unroll
            for (int j = 0; j < 4; ++j) {
                float z = __builtin_fmaf(acc[mi][t][j], rstd, nmrs);
                float v = __builtin_fmaf(z, g4[j], b4[j]);
                o[j] = nonsat(v);
            }
            *(f32x4*)(orow + n) = o;
        }
    }
}

// ---------- fallback (no workspace) ----------
__global__ __launch_bounds__(256) void fallback_fwd(
    const float* __restrict__ x, const float* __restrict__ Wf,
    const float* __restrict__ bias, const float* __restrict__ gamma,
    const float* __restrict__ beta, const float* __restrict__ pe,
    float* __restrict__ out)
{
    const int tid  = threadIdx.x;
    const int wave = tid >> 6;
    const int lane = tid & 63;
    const int lrow = lane & 15;
    const int kgrp = lane >> 4;
    const int n0   = wave * 128;
    const int m0   = blockIdx.x * 32;

    f32x4 acc[2][8];
    #pragma unroll
    for (int a = 0; a < 2; ++a)
        #pragma unroll
        for (int t = 0; t < 8; ++t) acc[a][t] = (f32x4){0.f,0.f,0.f,0.f};

    const int mA[2] = { m0 + lrow, m0 + 16 + lrow };
    for (int ks = 0; ks < 32; ++ks) {
        const int kb = ks * 32 + kgrp * 8;
        bf16x8 afrag[2];
        #pragma unroll
        for (int a = 0; a < 2; ++a) {
            const float* src = (kb < 512)
                ? (x  + (size_t)mA[a] * 512 + kb)
                : (pe + (size_t)(mA[a] >> 3) * 512 + (kb - 512));
            f32x4 lo = *(const f32x4*)src;
            f32x4 hi = *(const f32x4*)(src + 4);
            union { u32x4 u; bf16x8 s; } cv;
            cv.u[0] = cvt_pk2(lo[0], lo[1]); cv.u[1] = cvt_pk2(lo[2], lo[3]);
            cv.u[2] = cvt_pk2(hi[0], hi[1]); cv.u[3] = cvt_pk2(hi[2], hi[3]);
            afrag[a] = cv.s;
        }
        #pragma unroll
        for (int t = 0; t < 8; ++t) {
            const int n = n0 + t * 16 + lrow;
            const float* wsrc = Wf + (size_t)n * KFULL + kb;
            f32x4 lo = *(const f32x4*)wsrc;
            f32x4 hi = *(const f32x4*)(wsrc + 4);
            union { u32x4 u; bf16x8 s; } cv;
            cv.u[0] = cvt_pk2(lo[0], lo[1]); cv.u[1] = cvt_pk2(lo[2], lo[3]);
            cv.u[2] = cvt_pk2(hi[0], hi[1]); cv.u[3] = cvt_pk2(hi[2], hi[3]);
            acc[0][t] = __builtin_amdgcn_mfma_f32_16x16x32_bf16(afrag[0], cv.s, acc[0][t], 0, 0, 0);
            acc[1][t] = __builtin_amdgcn_mfma_f32_16x16x32_bf16(afrag[1], cv.s, acc[1][t], 0, 0, 0);
        }
    }
    __shared__ float red[4][32][2];
    float bcol[8], gcol[8], ecol[8];
    #pragma unroll
    for (int t = 0; t < 8; ++t) {
        const int n = n0 + t * 16 + lrow;
        bcol[t] = bias[n]; gcol[t] = gamma[n]; ecol[t] = beta[n];
    }
    #pragma unroll
    for (int a = 0; a < 2; ++a)
        #pragma unroll
        for (int t = 0; t < 8; ++t)
            #pragma unroll
            for (int j = 0; j < 4; ++j) acc[a][t][j] += bcol[t];
    float sm[2][4], sq[2][4];
    #pragma unroll
    for (int a = 0; a < 2; ++a)
        #pragma unroll
        for (int j = 0; j < 4; ++j) {
            float s = 0.f, q = 0.f;
            #pragma unroll
            for (int t = 0; t < 8; ++t) { float v = acc[a][t][j]; s += v; q += v * v; }
            #pragma unroll
            for (int msk = 1; msk <= 8; msk <<= 1) {
                s += __shfl_xor(s, msk, 64);
                q += __shfl_xor(q, msk, 64);
            }
            sm[a][j] = s; sq[a][j] = q;
        }
    if (lrow == 0) {
        #pragma unroll
        for (int a = 0; a < 2; ++a)
            #pragma unroll
            for (int j = 0; j < 4; ++j) {
                int r = a * 16 + kgrp * 4 + j;
                red[wave][r][0] = sm[a][j];
                red[wave][r][1] = sq[a][j];
            }
    }
    __syncthreads();
    #pragma unroll
    for (int a = 0; a < 2; ++a)
        #pragma unroll
        for (int j = 0; j < 4; ++j) {
            const int r = a * 16 + kgrp * 4 + j;
            float Ss = red[0][r][0] + red[1][r][0] + red[2][r][0] + red[3][r][0];
            float Qs = red[0][r][1] + red[1][r][1] + red[2][r][1] + red[3][r][1];
            float mean = Ss * (1.0f / 512.0f);
            float var  = Qs * (1.0f / 512.0f) - mean * mean;
            float rstd = rsqrtf(var + 1e-5f);
            const int m = m0 + a * 16 + kgrp * 4 + j;
            float* orow = out + (size_t)m * 512;
            #pragma unroll
            for (int t = 0; t < 8; ++t) {
                const int n = n0 + t * 16 + lrow;
                float v = (acc[a][t][j] - mean) * rstd * gcol[t] + ecol[t];
                orow[n] = nonsat(v);
            }
        }
}

extern "C" void kernel_launch(void* const* d_in, const int* in_sizes, int n_in,
                              void* d_out, int out_size, void* d_ws, size_t ws_size,
                              hipStream_t stream) {
    const float* x     = (const float*)d_in[0];
    const float* W     = (const float*)d_in[1];
    const float* bias  = (const float*)d_in[2];
    const float* gamma = (const float*)d_in[3];
    const float* beta  = (const float*)d_in[4];
    const float* pe    = (const float*)d_in[5];
    float* out = (float*)d_out;

    const size_t WBF_BYTES = (size_t)KFULL * DMODEL * sizeof(short);   // 1 MB

    if (ws_size >= WBF_BYTES) {
        short* Wbf = (short*)d_ws;
        cvt_w<<<dim3((DMODEL * KFULL) / (256 * 8)), dim3(256), 0, stream>>>(W, Wbf);
        main_fused<<<dim3(MROWS / 128), dim3(512), 0, stream>>>(x, Wbf, pe, bias, gamma, beta, out);
    } else {
        fallback_fwd<<<dim3(MROWS / 32), dim3(256), 0, stream>>>(x, W, bias, gamma, beta, pe, out);
    }
}

// Round 20
// 54.413 us; speedup vs baseline: 1.0060x; 1.0060x over previous
//
#include <hip/hip_runtime.h>
#include <hip/hip_bf16.h>

#define SEQL 4096
#define MROWS 32768
#define DMODEL 512
#define KFULL 1024
#define PSTR 516   // padded P_lds row stride (floats); 516*4B is 16B-aligned, lane-bank stride 4

typedef __attribute__((ext_vector_type(8))) short bf16x8;
typedef __attribute__((ext_vector_type(4))) unsigned u32x4;
typedef __attribute__((ext_vector_type(4))) float f32x4;

__device__ __forceinline__ unsigned cvt_pk2(float a, float b) {
    unsigned r;
    asm("v_cvt_pk_bf16_f32 %0, %1, %2" : "=v"(r) : "v"(a), "v"(b));
    return r;
}

__device__ __forceinline__ float nonsat(float x) {
    float y = x;
    #pragma unroll
    for (int i = 0; i < 5; ++i) {
        float y2  = y * y;
        float num = __builtin_fmaf(y2 * y, 0.66666667f, x);
        y = num * __builtin_amdgcn_rcpf(y2 + 1.0f);
    }
    return y;
}

// W (512x1024 f32 [n][k]) -> fragment-tiled bf16:
// frag f = (k/32)*32 + (n/16); lane = ((k/8)&3)*16 + (n&15); elems k..k+7.
__global__ __launch_bounds__(256) void cvt_w(const float* __restrict__ W,
                                             short* __restrict__ Wbf) {
    int t8 = blockIdx.x * 256 + threadIdx.x;
    int n = t8 >> 7;
    int k = (t8 & 127) << 3;
    f32x4 lo = *(const f32x4*)(W + (size_t)n * KFULL + k);
    f32x4 hi = *(const f32x4*)(W + (size_t)n * KFULL + k + 4);
    u32x4 v;
    v[0] = cvt_pk2(lo[0], lo[1]); v[1] = cvt_pk2(lo[2], lo[3]);
    v[2] = cvt_pk2(hi[0], hi[1]); v[3] = cvt_pk2(hi[2], hi[3]);
    int f    = (k >> 5) * 32 + (n >> 4);
    int lane = ((k >> 3) & 3) * 16 + (n & 15);
    *(u32x4*)(Wbf + (size_t)f * 512 + lane * 8) = v;
}

// main (fully fused): out = nonsat(LN(x @ W1^T + (pe @ W2^T + bias)[m>>3]))
// 128 rows x 512 cols per block, 8 waves (2m x 4n), BK=32, grid 256 (1/CU).
// Phase 0: in-kernel pe-GEMM (block-exclusive 16 P-rows), 2-deep pipelined.
// Phase 1: verified K-loop — double-buffered LDS W (frag layout, flat copy)
//   + x (frag layout, write-side permutation), 1 barrier/k-step.
__global__ __launch_bounds__(512, 2) void main_fused(
    const float* __restrict__ x, const short* __restrict__ Wbf,
    const float* __restrict__ pe, const float* __restrict__ bias,
    const float* __restrict__ gamma, const float* __restrict__ beta,
    float* __restrict__ out)
{
    __shared__ __align__(16) short Wl[2][16384];   // 64 KB
    __shared__ __align__(16) short As[2][4096];    // 16 KB
    __shared__ float P_lds[16 * PSTR];             // 33 KB (padded stride)
    __shared__ float GB[2][512];                   // 4 KB
    __shared__ float red[4][128][2];               // 4 KB

    const int tid  = threadIdx.x;
    const int wid  = tid >> 6;
    const int wm   = wid >> 2;
    const int wn   = wid & 3;
    const int lane = tid & 63;
    const int l4   = lane & 15;
    const int kg   = lane >> 4;
    const int m0   = blockIdx.x * 128;
    const int l0   = m0 >> 3;           // 16 exclusive P rows per block

    // x: thread -> row tid/4, k-chunk (tid&3)*8 (8 fp32 = 32B, coalesced)
    const float* xp = x + (size_t)(m0 + (tid >> 2)) * DMODEL + (tid & 3) * 8;
    const int as_adr = wid * 512 + ((tid & 3) * 16 + ((tid >> 2) & 15)) * 8;

    u32x4 wr[4];
    f32x4 xr0, xr1;

    #define LOADS(kf)  do {                                                     \
        const short* wg = Wbf + (size_t)(kf) * 16384 + tid * 8;                 \
        wr[0] = *(const u32x4*)(wg);                                            \
        wr[1] = *(const u32x4*)(wg + 4096);                                     \
        wr[2] = *(const u32x4*)(wg + 8192);                                     \
        wr[3] = *(const u32x4*)(wg + 12288);                                    \
        xr0 = *(const f32x4*)(xp + (kf) * 32);                                  \
        xr1 = *(const f32x4*)(xp + (kf) * 32 + 4);                              \
    } while (0)

    #define WRITES(b)  do {                                                     \
        *(u32x4*)&Wl[b][tid * 8]         = wr[0];                               \
        *(u32x4*)&Wl[b][tid * 8 + 4096]  = wr[1];                               \
        *(u32x4*)&Wl[b][tid * 8 + 8192]  = wr[2];                               \
        *(u32x4*)&Wl[b][tid * 8 + 12288] = wr[3];                               \
        u32x4 v;                                                                \
        v[0] = cvt_pk2(xr0[0], xr0[1]); v[1] = cvt_pk2(xr0[2], xr0[3]);         \
        v[2] = cvt_pk2(xr1[0], xr1[1]); v[3] = cvt_pk2(xr1[2], xr1[3]);         \
        *(u32x4*)&As[b][as_adr] = v;                                            \
    } while (0)

    // ================= Phase 0: pipelined pe-GEMM -> P_lds ================
    {
        const float* peb = pe + (size_t)(l0 + l4) * DMODEL + kg * 8;

        #define PH0_LOAD(kf, AW, PL, PH) do {                                    \
            _Pragma("unroll")                                                    \
            for (int t_ = 0; t_ < 4; ++t_)                                       \
                AW[t_] = *(const bf16x8*)(Wbf +                                  \
                    (size_t)((16 + (kf)) * 32 + wid * 4 + t_) * 512 + lane * 8); \
            PL = *(const f32x4*)(peb + (kf) * 32);                               \
            PH = *(const f32x4*)(peb + (kf) * 32 + 4);                           \
        } while (0)

        bf16x8 awA[4], awB[4];
        f32x4 plA, phA, plB, phB;
        f32x4 accp[4];
        #pragma unroll
        for (int t = 0; t < 4; ++t) accp[t] = (f32x4){0.f, 0.f, 0.f, 0.f};

        PH0_LOAD(0, awA, plA, phA);
        LOADS(0);   // phase-1 step-0 loads land during phase-0 compute

        #pragma unroll
        for (int kf = 0; kf < 16; ++kf) {
            if ((kf & 1) == 0) {
                if (kf < 15) PH0_LOAD(kf + 1, awB, plB, phB);
                union { u32x4 u; bf16x8 s; } cv;
                cv.u[0] = cvt_pk2(plA[0], plA[1]); cv.u[1] = cvt_pk2(plA[2], plA[3]);
                cv.u[2] = cvt_pk2(phA[0], phA[1]); cv.u[3] = cvt_pk2(phA[2], phA[3]);
                #pragma unroll
                for (int t = 0; t < 4; ++t)
                    accp[t] = __builtin_amdgcn_mfma_f32_16x16x32_bf16(awA[t], cv.s, accp[t], 0, 0, 0);
            } else {
                if (kf < 15) PH0_LOAD(kf + 1, awA, plA, phA);
                union { u32x4 u; bf16x8 s; } cv;
                cv.u[0] = cvt_pk2(plB[0], plB[1]); cv.u[1] = cvt_pk2(plB[2], plB[3]);
                cv.u[2] = cvt_pk2(phB[0], phB[1]); cv.u[3] = cvt_pk2(phB[2], phB[3]);
                #pragma unroll
                for (int t = 0; t < 4; ++t)
                    accp[t] = __builtin_amdgcn_mfma_f32_16x16x32_bf16(awB[t], cv.s, accp[t], 0, 0, 0);
            }
        }
        #undef PH0_LOAD

        // C layout: col(l4) = pe row l, row(kg*4+j) = n within frag
        #pragma unroll
        for (int t = 0; t < 4; ++t) {
            int n = wid * 64 + t * 16 + kg * 4;
            f32x4 b4 = *(const f32x4*)(bias + n);
            *(f32x4*)&P_lds[l4 * PSTR + n] = accp[t] + b4;
        }
    }

    // ================= Phase 1: main GEMM ===================
    f32x4 acc[4][8];
    #pragma unroll
    for (int mi = 0; mi < 4; ++mi)
        #pragma unroll
        for (int t = 0; t < 8; ++t) acc[mi][t] = (f32x4){0.f,0.f,0.f,0.f};

    WRITES(0);
    LOADS(1);

    f32x4 gb;

    #pragma unroll
    for (int kf = 0; kf < 16; ++kf) {
        const int cur = kf & 1;
        __syncthreads();
        if (kf < 15) WRITES(cur ^ 1);
        if (kf < 14) LOADS(kf + 2);
        if (kf == 13) {
            if (tid < 256) {
                const float* gsrc = (tid < 128) ? (gamma + tid * 4) : (beta + (tid - 128) * 4);
                gb = *(const f32x4*)gsrc;
            }
        }
        bf16x8 aw[8];
        #pragma unroll
        for (int t = 0; t < 8; ++t)
            aw[t] = *(const bf16x8*)&Wl[cur][(wn * 8 + t) * 512 + lane * 8];
        bf16x8 bx[4];
        #pragma unroll
        for (int mi = 0; mi < 4; ++mi)
            bx[mi] = *(const bf16x8*)&As[cur][(wm * 4 + mi) * 512 + lane * 8];
        __builtin_amdgcn_s_setprio(1);
        #pragma unroll
        for (int t = 0; t < 8; ++t)
            #pragma unroll
            for (int mi = 0; mi < 4; ++mi)
                acc[mi][t] = __builtin_amdgcn_mfma_f32_16x16x32_bf16(aw[t], bx[mi], acc[mi][t], 0, 0, 0);
        __builtin_amdgcn_s_setprio(0);
    }
    #undef LOADS
    #undef WRITES

    // ---- stage gamma/beta to LDS (P already resident in P_lds) ----
    if (tid < 256) {
        if (tid < 128) *(f32x4*)&GB[0][tid * 4]         = gb;
        else           *(f32x4*)&GB[1][(tid - 128) * 4] = gb;
    }
    __syncthreads();

    // ---- add P (broadcast LDS reads) ----
    #pragma unroll
    for (int mi = 0; mi < 4; ++mi) {
        int lp = wm * 8 + mi * 2 + (l4 >> 3);
        #pragma unroll
        for (int t = 0; t < 8; ++t) {
            f32x4 p4 = *(const f32x4*)&P_lds[lp * PSTR + wn * 128 + t * 16 + kg * 4];
            acc[mi][t] += p4;
        }
    }

    // ---- LN stats ----
    float S[4], Q[4];
    #pragma unroll
    for (int mi = 0; mi < 4; ++mi) {
        float s = 0.f, q = 0.f;
        #pragma unroll
        for (int t = 0; t < 8; ++t)
            #pragma unroll
            for (int j = 0; j < 4; ++j) {
                float v = acc[mi][t][j];
                s += v; q = __builtin_fmaf(v, v, q);
            }
        s += __shfl_xor(s, 16); q += __shfl_xor(q, 16);
        s += __shfl_xor(s, 32); q += __shfl_xor(q, 32);
        S[mi] = s; Q[mi] = q;
    }
    if (lane < 16) {
        #pragma unroll
        for (int mi = 0; mi < 4; ++mi) {
            red[wn][wm * 64 + mi * 16 + l4][0] = S[mi];
            red[wn][wm * 64 + mi * 16 + l4][1] = Q[mi];
        }
    }
    __syncthreads();

    // ---- normalize + nonsat + stores ----
    #pragma unroll
    for (int mi = 0; mi < 4; ++mi) {
        int r = wm * 64 + mi * 16 + l4;
        float Ss = red[0][r][0] + red[1][r][0] + red[2][r][0] + red[3][r][0];
        float Qs = red[0][r][1] + red[1][r][1] + red[2][r][1] + red[3][r][1];
        float mean = Ss * (1.0f / 512.0f);
        float var  = Qs * (1.0f / 512.0f) - mean * mean;
        float rstd = rsqrtf(var + 1e-5f);
        float nmrs = -mean * rstd;
        float* orow = out + (size_t)(m0 + r) * DMODEL;
        #pragma unroll
        for (int t = 0; t < 8; ++t) {
            int n = wn * 128 + t * 16 + kg * 4;
            f32x4 g4 = *(const f32x4*)&GB[0][n];
            f32x4 b4 = *(const f32x4*)&GB[1][n];
            f32x4 o;
            #pragma unroll
            for (int j = 0; j < 4; ++j) {
                float z = __builtin_fmaf(acc[mi][t][j], rstd, nmrs);
                float v = __builtin_fmaf(z, g4[j], b4[j]);
                o[j] = nonsat(v);
            }
            *(f32x4*)(orow + n) = o;
        }
    }
}

// ---------- fallback (no workspace) ----------
__global__ __launch_bounds__(256) void fallback_fwd(
    const float* __restrict__ x, const float* __restrict__ Wf,
    const float* __restrict__ bias, const float* __restrict__ gamma,
    const float* __restrict__ beta, const float* __restrict__ pe,
    float* __restrict__ out)
{
    const int tid  = threadIdx.x;
    const int wave = tid >> 6;
    const int lane = tid & 63;
    const int lrow = lane & 15;
    const int kgrp = lane >> 4;
    const int n0   = wave * 128;
    const int m0   = blockIdx.x * 32;

    f32x4 acc[2][8];
    #pragma unroll
    for (int a = 0; a < 2; ++a)
        #pragma unroll
        for (int t = 0; t < 8; ++t) acc[a][t] = (f32x4){0.f,0.f,0.f,0.f};

    const int mA[2] = { m0 + lrow, m0 + 16 + lrow };
    for (int ks = 0; ks < 32; ++ks) {
        const int kb = ks * 32 + kgrp * 8;
        bf16x8 afrag[2];
        #pragma unroll
        for (int a = 0; a < 2; ++a) {
            const float* src = (kb < 512)
                ? (x  + (size_t)mA[a] * 512 + kb)
                : (pe + (size_t)(mA[a] >> 3) * 512 + (kb - 512));
            f32x4 lo = *(const f32x4*)src;
            f32x4 hi = *(const f32x4*)(src + 4);
            union { u32x4 u; bf16x8 s; } cv;
            cv.u[0] = cvt_pk2(lo[0], lo[1]); cv.u[1] = cvt_pk2(lo[2], lo[3]);
            cv.u[2] = cvt_pk2(hi[0], hi[1]); cv.u[3] = cvt_pk2(hi[2], hi[3]);
            afrag[a] = cv.s;
        }
        #pragma unroll
        for (int t = 0; t < 8; ++t) {
            const int n = n0 + t * 16 + lrow;
            const float* wsrc = Wf + (size_t)n * KFULL + kb;
            f32x4 lo = *(const f32x4*)wsrc;
            f32x4 hi = *(const f32x4*)(wsrc + 4);
            union { u32x4 u; bf16x8 s; } cv;
            cv.u[0] = cvt_pk2(lo[0], lo[1]); cv.u[1] = cvt_pk2(lo[2], lo[3]);
            cv.u[2] = cvt_pk2(hi[0], hi[1]); cv.u[3] = cvt_pk2(hi[2], hi[3]);
            acc[0][t] = __builtin_amdgcn_mfma_f32_16x16x32_bf16(afrag[0], cv.s, acc[0][t], 0, 0, 0);
            acc[1][t] = __builtin_amdgcn_mfma_f32_16x16x32_bf16(afrag[1], cv.s, acc[1][t], 0, 0, 0);
        }
    }
    __shared__ float red[4][32][2];
    float bcol[8], gcol[8], ecol[8];
    #pragma unroll
    for (int t = 0; t < 8; ++t) {
        const int n = n0 + t * 16 + lrow;
        bcol[t] = bias[n]; gcol[t] = gamma[n]; ecol[t] = beta[n];
    }
    #pragma unroll
    for (int a = 0; a < 2; ++a)
        #pragma unroll
        for (int t = 0; t < 8; ++t)
            #pragma unroll
            for (int j = 0; j < 4; ++j) acc[a][t][j] += bcol[t];
    float sm[2][4], sq[2][4];
    #pragma unroll
    for (int a = 0; a < 2; ++a)
        #pragma unroll
        for (int j = 0; j < 4; ++j) {
            float s = 0.f, q = 0.f;
            #pragma unroll
            for (int t = 0; t < 8; ++t) { float v = acc[a][t][j]; s += v; q += v * v; }
            #pragma unroll
            for (int msk = 1; msk <= 8; msk <<= 1) {
                s += __shfl_xor(s, msk, 64);
                q += __shfl_xor(q, msk, 64);
            }
            sm[a][j] = s; sq[a][j] = q;
        }
    if (lrow == 0) {
        #pragma unroll
        for (int a = 0; a < 2; ++a)
            #pragma unroll
            for (int j = 0; j < 4; ++j) {
                int r = a * 16 + kgrp * 4 + j;
                red[wave][r][0] = sm[a][j];
                red[wave][r][1] = sq[a][j];
            }
    }
    __syncthreads();
    #pragma unroll
    for (int a = 0; a < 2; ++a)
        #pragma unroll
        for (int j = 0; j < 4; ++j) {
            const int r = a * 16 + kgrp * 4 + j;
            float Ss = red[0][r][0] + red[1][r][0] + red[2][r][0] + red[3][r][0];
            float Qs = red[0][r][1] + red[1][r][1] + red[2][r][1] + red[3][r][1];
            float mean = Ss * (1.0f / 512.0f);
            float var  = Qs * (1.0f / 512.0f) - mean * mean;
            float rstd = rsqrtf(var + 1e-5f);
            const int m = m0 + a * 16 + kgrp * 4 + j;
            float* orow = out + (size_t)m * 512;
            #pragma unroll
            for (int t = 0; t < 8; ++t) {
                const int n = n0 + t * 16 + lrow;
                float v = (acc[a][t][j] - mean) * rstd * gcol[t] + ecol[t];
                orow[n] = nonsat(v);
            }
        }
}

extern "C" void kernel_launch(void* const* d_in, const int* in_sizes, int n_in,
                              void* d_out, int out_size, void* d_ws, size_t ws_size,
                              hipStream_t stream) {
    const float* x     = (const float*)d_in[0];
    const float* W     = (const float*)d_in[1];
    const float* bias  = (const float*)d_in[2];
    const float* gamma = (const float*)d_in[3];
    const float* beta  = (const float*)d_in[4];
    const float* pe    = (const float*)d_in[5];
    float* out = (float*)d_out;

    const size_t WBF_BYTES = (size_t)KFULL * DMODEL * sizeof(short);   // 1 MB

    if (ws_size >= WBF_BYTES) {
        short* Wbf = (short*)d_ws;
        cvt_w<<<dim3((DMODEL * KFULL) / (256 * 8)), dim3(256), 0, stream>>>(W, Wbf);
        main_fused<<<dim3(MROWS / 128), dim3(512), 0, stream>>>(x, Wbf, pe, bias, gamma, beta, out);
    } else {
        fallback_fwd<<<dim3(MROWS / 32), dim3(256), 0, stream>>>(x, W, bias, gamma, beta, pe, out);
    }
}